// Round 2
// baseline (1430.535 us; speedup 1.0000x reference)
//
#include <hip/hip_runtime.h>
#include <hip/hip_bf16.h>

typedef unsigned short u16;
typedef __bf16 bf16x8 __attribute__((ext_vector_type(8)));
typedef float f32x4 __attribute__((ext_vector_type(4)));

#if __has_builtin(__builtin_amdgcn_exp2f)
#define EXP2F(x) __builtin_amdgcn_exp2f(x)
#else
#define EXP2F(x) exp2f(x)
#endif

// log2(e)/32  (softmax scale 1/sqrt(1024) folded into exp2 domain)
#define FA_C32 0.045084220027780106f

__device__ __forceinline__ f32x4 mfma16(bf16x8 a, bf16x8 b, f32x4 c) {
  return __builtin_amdgcn_mfma_f32_16x16x32_bf16(a, b, c, 0, 0, 0);
}
__device__ __forceinline__ unsigned pk2bf(float a, float b) {
  union { __bf16 h[2]; unsigned u; } x;
  x.h[0] = (__bf16)a; x.h[1] = (__bf16)b;
  return x.u;
}
__device__ __forceinline__ u16 bf1(float a) {
  union { __bf16 h; u16 u; } x; x.h = (__bf16)a; return x.u;
}

typedef __attribute__((address_space(1))) const unsigned int gas_u32;
typedef __attribute__((address_space(3))) unsigned int las_u32;
__device__ __forceinline__ void gl_lds16(const u16* g, u16* l) {
  __builtin_amdgcn_global_load_lds((gas_u32*)g, (las_u32*)l, 16, 0, 0);
}

// ---------------- cast fp32 -> bf16, 8 elems/thread ----------------
__global__ __launch_bounds__(256) void cast_bf16_k(const float* __restrict__ src,
                                                   u16* __restrict__ dst, int n8) {
  int i = blockIdx.x * 256 + threadIdx.x;
  if (i >= n8) return;
  const float4* s4 = (const float4*)src;
  float4 a = s4[i * 2], b = s4[i * 2 + 1];
  uint4 o;
  o.x = pk2bf(a.x, a.y); o.y = pk2bf(a.z, a.w);
  o.z = pk2bf(b.x, b.y); o.w = pk2bf(b.z, b.w);
  ((uint4*)dst)[i] = o;
}

// ---------------- QKV projection GEMM (m97-structure) ----------------
__global__ __launch_bounds__(256) void gemm_qkv(const u16* __restrict__ Xb,
    const u16* __restrict__ Wb, const float* __restrict__ bias,
    u16* __restrict__ Qo, u16* __restrict__ Ko, u16* __restrict__ Vt) {
  __shared__ u16 As[128 * 64];
  __shared__ u16 Bs[128 * 64];
  const int tid = threadIdx.x, lane = tid & 63, w = tid >> 6;
  const int m0 = blockIdx.x * 128, n0 = blockIdx.y * 128;
  const int wr = w >> 1, wc = w & 1;

  f32x4 acc[4][4];
#pragma unroll
  for (int i = 0; i < 4; ++i)
#pragma unroll
    for (int j = 0; j < 4; ++j) acc[i][j] = 0.f;

  const int srow = w * 32 + (lane >> 3);
  const int skol = (lane & 7) * 8;
  const u16* ag = Xb + (size_t)(m0 + srow) * 1024 + skol;
  const u16* bg = Wb + (size_t)(n0 + srow) * 1024 + skol;
  u16* as_l = As + (w * 4) * 512;
  u16* bs_l = Bs + (w * 4) * 512;

  for (int kt = 0; kt < 16; ++kt) {
    __syncthreads();
#pragma unroll
    for (int i = 0; i < 4; ++i) {
      gl_lds16(ag + i * 8 * 1024 + kt * 64, as_l + i * 512);
      gl_lds16(bg + i * 8 * 1024 + kt * 64, bs_l + i * 512);
    }
    __syncthreads();
#pragma unroll
    for (int kc = 0; kc < 2; ++kc) {
      bf16x8 af[4], bfr[4];
#pragma unroll
      for (int rf = 0; rf < 4; ++rf)
        af[rf] = *(const bf16x8*)(As + (wr * 64 + rf * 16 + (lane & 15)) * 64 + kc * 32 + (lane >> 4) * 8);
#pragma unroll
      for (int cf = 0; cf < 4; ++cf)
        bfr[cf] = *(const bf16x8*)(Bs + (wc * 64 + cf * 16 + (lane & 15)) * 64 + kc * 32 + (lane >> 4) * 8);
#pragma unroll
      for (int rf = 0; rf < 4; ++rf)
#pragma unroll
        for (int cf = 0; cf < 4; ++cf)
          acc[rf][cf] = mfma16(af[rf], bfr[cf], acc[rf][cf]);
    }
  }

  float bv[4];
#pragma unroll
  for (int cf = 0; cf < 4; ++cf) bv[cf] = bias[n0 + wc * 64 + cf * 16 + (lane & 15)];
  const int region = n0 >> 10;
  const int ncol = (n0 & 1023) + wc * 64;
  if (region < 2) {
    u16* dst = region ? Ko : Qo;
#pragma unroll
    for (int rf = 0; rf < 4; ++rf) {
      int m = m0 + wr * 64 + rf * 16 + (lane >> 4) * 4;
#pragma unroll
      for (int r = 0; r < 4; ++r)
#pragma unroll
        for (int cf = 0; cf < 4; ++cf)
          dst[(size_t)(m + r) * 1024 + ncol + cf * 16 + (lane & 15)] = bf1(acc[rf][cf][r] + bv[cf]);
    }
  } else {
#pragma unroll
    for (int rf = 0; rf < 4; ++rf) {
      int m = m0 + wr * 64 + rf * 16 + (lane >> 4) * 4;
      int bb = m >> 12, s = m & 4095;
#pragma unroll
      for (int cf = 0; cf < 4; ++cf) {
        int d = ncol + cf * 16 + (lane & 15);
        uint2 v;
        v.x = pk2bf(acc[rf][cf][0] + bv[cf], acc[rf][cf][1] + bv[cf]);
        v.y = pk2bf(acc[rf][cf][2] + bv[cf], acc[rf][cf][3] + bv[cf]);
        *(uint2*)&Vt[(size_t)(bb * 1024 + d) * 4096 + s] = v;
      }
    }
  }
}

// ---------------- flash attention v2: BQ=64, BK=128, 8 waves ----------------
// QK: wave = key-group (16 keys x all 64 q)  -> each K element loaded ONCE per block.
// Depth-8 register prefetch on K (QK) and V (PV). PV: wave = 128-d slice.
__global__ __launch_bounds__(512) void flash_k(const u16* __restrict__ Qg,
    const u16* __restrict__ Kg, const u16* __restrict__ Vtg,
    float* __restrict__ Og) {
  __shared__ u16 Qs[64 * 1024];     // 128 KiB, XOR-swizzled
  __shared__ u16 Ps[64 * 128];      // 16 KiB, swizzled
  __shared__ float m2s[64], ls[64], cs[64];
  __shared__ float pmaxp[8][64], lsump[8][64];
  __shared__ int allc1;

  const int tid = threadIdx.x, lane = tid & 63, wid = tid >> 6;
  const int bid = blockIdx.x;
  const int xcd = bid & 7, idx = bid >> 3;
  const int batch = xcd >> 1, qblk = (xcd & 1) * 32 + idx;
  const u16* Qp = Qg + (size_t)(batch * 4096 + qblk * 64) * 1024;
  const u16* Kp = Kg + (size_t)batch * 4096 * 1024;
  const u16* Vp = Vtg + (size_t)batch * 1024 * 4096;
  float* Op = Og + (size_t)(batch * 4096 + qblk * 64) * 1024;

  // stage Q into swizzled LDS
#pragma unroll
  for (int i = 0; i < 16; ++i) {
    int c = i * 512 + tid;
    int row = c >> 7, h8 = c & 127;
    uint4 v = *(const uint4*)(Qp + row * 1024 + h8 * 8);
    *(uint4*)((char*)Qs + ((row * 2048 + h8 * 16) ^ ((row & 7) << 4))) = v;
  }
  if (tid < 64) { m2s[tid] = -1e30f; ls[tid] = 0.f; }

  f32x4 O[4][8];
#pragma unroll
  for (int a = 0; a < 4; ++a)
#pragma unroll
    for (int d = 0; d < 8; ++d) O[a][d] = 0.f;

  const int l15 = lane & 15, lhi = lane >> 4;
  const int qswz = (lane & 7) << 4;
  int qb[4];
#pragma unroll
  for (int qf = 0; qf < 4; ++qf) qb[qf] = (qf * 16 + l15) * 2048 + lhi * 16;
  const int dw = wid * 128;
  __syncthreads();

  for (int t = 0; t < 32; ++t) {
    // ---- QK^T: this wave owns keys [t*128 + wid*16 .. +16) for ALL 64 q ----
    f32x4 Sv[4];
#pragma unroll
    for (int qf = 0; qf < 4; ++qf) Sv[qf] = 0.f;
    const u16* kp0 = Kp + (size_t)(t * 128 + wid * 16 + l15) * 1024 + lhi * 8;
    bf16x8 kaA[8], kaB[8];
#pragma unroll
    for (int j = 0; j < 8; ++j) kaA[j] = *(const bf16x8*)(kp0 + j * 32);

#define QK_G(CUR, NXT, G, PF)                                                   \
    {                                                                           \
      _Pragma("unroll")                                                         \
      for (int j = 0; j < 8; ++j) {                                             \
        if (PF) NXT[j] = *(const bf16x8*)(kp0 + ((G + 1) * 8 + j) * 32);        \
        const int kc = G * 8 + j;                                               \
        _Pragma("unroll")                                                       \
        for (int qf = 0; qf < 4; ++qf) {                                        \
          bf16x8 qfr = *(const bf16x8*)((const char*)Qs + ((qb[qf] + kc * 64) ^ qswz)); \
          Sv[qf] = mfma16(CUR[j], qfr, Sv[qf]);                                 \
        }                                                                       \
      }                                                                         \
    }
    QK_G(kaA, kaB, 0, 1)
    QK_G(kaB, kaA, 1, 1)
    QK_G(kaA, kaB, 2, 1)
    QK_G(kaB, kaA, 3, 0)
#undef QK_G

    // per-q max over this wave's 16 keys
    float pm[4];
#pragma unroll
    for (int qf = 0; qf < 4; ++qf) {
      float p = fmaxf(fmaxf(Sv[qf][0], Sv[qf][1]), fmaxf(Sv[qf][2], Sv[qf][3]));
      p = fmaxf(p, __shfl_xor(p, 16, 64));
      p = fmaxf(p, __shfl_xor(p, 32, 64));
      pm[qf] = p;
    }

    __syncthreads();                       // barA: prev PV done with Ps/cs
    if (lane < 16) {
#pragma unroll
      for (int qf = 0; qf < 4; ++qf) pmaxp[wid][qf * 16 + lane] = pm[qf];
    }
    __syncthreads();                       // barB
    if (tid < 64) {
      float mt = pmaxp[0][tid];
#pragma unroll
      for (int w2 = 1; w2 < 8; ++w2) mt = fmaxf(mt, pmaxp[w2][tid]);
      mt *= FA_C32;
      float mo = m2s[tid];
      float mn = fmaxf(mo, mt);
      float c = EXP2F(mo - mn);
      cs[tid] = c;
      m2s[tid] = mn;
      int f = __all(c == 1.0f);
      if (tid == 0) allc1 = f;
    }
    __syncthreads();                       // barC
    {
      float ls4[4];
#pragma unroll
      for (int qf = 0; qf < 4; ++qf) {
        int q = qf * 16 + l15;
        float mrow = m2s[q];
        float p0 = EXP2F(Sv[qf][0] * FA_C32 - mrow);
        float p1 = EXP2F(Sv[qf][1] * FA_C32 - mrow);
        float p2 = EXP2F(Sv[qf][2] * FA_C32 - mrow);
        float p3 = EXP2F(Sv[qf][3] * FA_C32 - mrow);
        ls4[qf] = (p0 + p1) + (p2 + p3);
        uint2 pv;
        pv.x = pk2bf(p0, p1);
        pv.y = pk2bf(p2, p3);
        *(uint2*)((char*)Ps + ((q * 256 + wid * 32 + lhi * 8) ^ qswz)) = pv;
      }
#pragma unroll
      for (int qf = 0; qf < 4; ++qf) {
        ls4[qf] += __shfl_xor(ls4[qf], 16, 64);
        ls4[qf] += __shfl_xor(ls4[qf], 32, 64);
      }
      if (lane < 16) {
#pragma unroll
        for (int qf = 0; qf < 4; ++qf) lsump[wid][qf * 16 + lane] = ls4[qf];
      }
    }
    __syncthreads();                       // barD: Ps/lsump/cs/flag ready
    if (tid < 64) {
      float s = lsump[0][tid];
#pragma unroll
      for (int w2 = 1; w2 < 8; ++w2) s += lsump[w2][tid];
      ls[tid] = ls[tid] * cs[tid] + s;
    }

    // ---- PV: this wave owns d-slice [wid*128 .. +128) ----
    if (!allc1) {
#pragma unroll
      for (int rf = 0; rf < 4; ++rf)
#pragma unroll
        for (int r = 0; r < 4; ++r) {
          float c = cs[rf * 16 + lhi * 4 + r];
#pragma unroll
          for (int dt = 0; dt < 8; ++dt) O[rf][dt][r] *= c;
        }
    }
    const u16* vp0 = Vp + (size_t)(dw + l15) * 4096 + t * 128 + lhi * 8;
    bf16x8 vfA[8], vfB[8];
#pragma unroll
    for (int j = 0; j < 8; ++j) vfA[j] = *(const bf16x8*)(vp0 + j * 16 * 4096);

#define PV_G(CUR, NXT, KC, PF)                                                  \
    {                                                                           \
      bf16x8 pa[4];                                                             \
      _Pragma("unroll")                                                         \
      for (int rf = 0; rf < 4; ++rf) {                                          \
        int prow = rf * 16 + l15;                                               \
        pa[rf] = *(const bf16x8*)((const char*)Ps + ((prow * 256 + KC * 64 + lhi * 16) ^ qswz)); \
      }                                                                         \
      _Pragma("unroll")                                                         \
      for (int j = 0; j < 8; ++j) {                                             \
        if (PF) NXT[j] = *(const bf16x8*)(vp0 + j * 16 * 4096 + (KC + 1) * 32); \
      }                                                                         \
      _Pragma("unroll")                                                         \
      for (int dt = 0; dt < 8; ++dt) {                                          \
        _Pragma("unroll")                                                       \
        for (int rf = 0; rf < 4; ++rf) O[rf][dt] = mfma16(pa[rf], CUR[dt], O[rf][dt]); \
      }                                                                         \
    }
    PV_G(vfA, vfB, 0, 1)
    PV_G(vfB, vfA, 1, 1)
    PV_G(vfA, vfB, 2, 1)
    PV_G(vfB, vfA, 3, 0)
#undef PV_G
  }

  __syncthreads();                         // ls final
#pragma unroll
  for (int rf = 0; rf < 4; ++rf)
#pragma unroll
    for (int r = 0; r < 4; ++r) {
      int row = rf * 16 + lhi * 4 + r;
      float linv = 1.0f / ls[row];
#pragma unroll
      for (int dt = 0; dt < 8; ++dt)
        Op[(size_t)row * 1024 + dw + dt * 16 + l15] = O[rf][dt][r] * linv;
    }
}

// ---------------- host ----------------
extern "C" void kernel_launch(void* const* d_in, const int* in_sizes, int n_in,
                              void* d_out, int out_size, void* d_ws, size_t ws_size,
                              hipStream_t stream) {
  const float* X = (const float*)d_in[0];   // [4,4096,1024]
  const float* W = (const float*)d_in[1];   // [3072,1024]
  const float* b = (const float*)d_in[2];   // [3072]
  float* out = (float*)d_out;               // [4,4096,1024] fp32
  char* ws = (char*)d_ws;
  u16* Xb = (u16*)(ws);                     // 33,554,432
  u16* Wb = (u16*)(ws + 33554432);          //  6,291,456
  u16* Qb = (u16*)(ws + 39845888);          // 33,554,432
  u16* Kb = (u16*)(ws + 73400320);          // 33,554,432
  u16* Vt = (u16*)(ws + 106954752);         // 33,554,432 (V transposed [4][1024][4096])

  cast_bf16_k<<<8192, 256, 0, stream>>>(X, Xb, 16777216 / 8);
  cast_bf16_k<<<1536, 256, 0, stream>>>(W, Wb, 3145728 / 8);
  dim3 gg(128, 24);
  gemm_qkv<<<gg, 256, 0, stream>>>(Xb, Wb, b, Qb, Kb, Vt);
  flash_k<<<256, 512, 0, stream>>>(Qb, Kb, Vt, out);
}

// Round 3
// 998.291 us; speedup vs baseline: 1.4330x; 1.4330x over previous
//
#include <hip/hip_runtime.h>
#include <hip/hip_bf16.h>

typedef unsigned short u16;
typedef __bf16 bf16x8 __attribute__((ext_vector_type(8)));
typedef float f32x4 __attribute__((ext_vector_type(4)));

#if __has_builtin(__builtin_amdgcn_exp2f)
#define EXP2F(x) __builtin_amdgcn_exp2f(x)
#else
#define EXP2F(x) exp2f(x)
#endif

// log2(e)/32  (softmax scale 1/sqrt(1024) folded into exp2 domain)
#define FA_C32 0.045084220027780106f

__device__ __forceinline__ f32x4 mfma16(bf16x8 a, bf16x8 b, f32x4 c) {
  return __builtin_amdgcn_mfma_f32_16x16x32_bf16(a, b, c, 0, 0, 0);
}
__device__ __forceinline__ unsigned pk2bf(float a, float b) {
  union { __bf16 h[2]; unsigned u; } x;
  x.h[0] = (__bf16)a; x.h[1] = (__bf16)b;
  return x.u;
}
__device__ __forceinline__ u16 bf1(float a) {
  union { __bf16 h; u16 u; } x; x.h = (__bf16)a; return x.u;
}

typedef __attribute__((address_space(1))) const unsigned int gas_u32;
typedef __attribute__((address_space(3))) unsigned int las_u32;
__device__ __forceinline__ void gl_lds16(const u16* g, u16* l) {
  __builtin_amdgcn_global_load_lds((gas_u32*)g, (las_u32*)l, 16, 0, 0);
}

// ---------------- cast fp32 -> bf16, 8 elems/thread ----------------
__global__ __launch_bounds__(256) void cast_bf16_k(const float* __restrict__ src,
                                                   u16* __restrict__ dst, int n8) {
  int i = blockIdx.x * 256 + threadIdx.x;
  if (i >= n8) return;
  const float4* s4 = (const float4*)src;
  float4 a = s4[i * 2], b = s4[i * 2 + 1];
  uint4 o;
  o.x = pk2bf(a.x, a.y); o.y = pk2bf(a.z, a.w);
  o.z = pk2bf(b.x, b.y); o.w = pk2bf(b.z, b.w);
  ((uint4*)dst)[i] = o;
}

// ---------------- QKV projection GEMM (m97-structure) ----------------
__global__ __launch_bounds__(256) void gemm_qkv(const u16* __restrict__ Xb,
    const u16* __restrict__ Wb, const float* __restrict__ bias,
    u16* __restrict__ Qo, u16* __restrict__ Ko, u16* __restrict__ Vt) {
  __shared__ u16 As[128 * 64];
  __shared__ u16 Bs[128 * 64];
  const int tid = threadIdx.x, lane = tid & 63, w = tid >> 6;
  const int m0 = blockIdx.x * 128, n0 = blockIdx.y * 128;
  const int wr = w >> 1, wc = w & 1;

  f32x4 acc[4][4];
#pragma unroll
  for (int i = 0; i < 4; ++i)
#pragma unroll
    for (int j = 0; j < 4; ++j) acc[i][j] = 0.f;

  const int srow = w * 32 + (lane >> 3);
  const int skol = (lane & 7) * 8;
  const u16* ag = Xb + (size_t)(m0 + srow) * 1024 + skol;
  const u16* bg = Wb + (size_t)(n0 + srow) * 1024 + skol;
  u16* as_l = As + (w * 4) * 512;
  u16* bs_l = Bs + (w * 4) * 512;

  for (int kt = 0; kt < 16; ++kt) {
    __syncthreads();
#pragma unroll
    for (int i = 0; i < 4; ++i) {
      gl_lds16(ag + i * 8 * 1024 + kt * 64, as_l + i * 512);
      gl_lds16(bg + i * 8 * 1024 + kt * 64, bs_l + i * 512);
    }
    __syncthreads();
#pragma unroll
    for (int kc = 0; kc < 2; ++kc) {
      bf16x8 af[4], bfr[4];
#pragma unroll
      for (int rf = 0; rf < 4; ++rf)
        af[rf] = *(const bf16x8*)(As + (wr * 64 + rf * 16 + (lane & 15)) * 64 + kc * 32 + (lane >> 4) * 8);
#pragma unroll
      for (int cf = 0; cf < 4; ++cf)
        bfr[cf] = *(const bf16x8*)(Bs + (wc * 64 + cf * 16 + (lane & 15)) * 64 + kc * 32 + (lane >> 4) * 8);
#pragma unroll
      for (int rf = 0; rf < 4; ++rf)
#pragma unroll
        for (int cf = 0; cf < 4; ++cf)
          acc[rf][cf] = mfma16(af[rf], bfr[cf], acc[rf][cf]);
    }
  }

  float bv[4];
#pragma unroll
  for (int cf = 0; cf < 4; ++cf) bv[cf] = bias[n0 + wc * 64 + cf * 16 + (lane & 15)];
  const int region = n0 >> 10;
  const int ncol = (n0 & 1023) + wc * 64;
  if (region < 2) {
    u16* dst = region ? Ko : Qo;
#pragma unroll
    for (int rf = 0; rf < 4; ++rf) {
      int m = m0 + wr * 64 + rf * 16 + (lane >> 4) * 4;
#pragma unroll
      for (int r = 0; r < 4; ++r)
#pragma unroll
        for (int cf = 0; cf < 4; ++cf)
          dst[(size_t)(m + r) * 1024 + ncol + cf * 16 + (lane & 15)] = bf1(acc[rf][cf][r] + bv[cf]);
    }
  } else {
#pragma unroll
    for (int rf = 0; rf < 4; ++rf) {
      int m = m0 + wr * 64 + rf * 16 + (lane >> 4) * 4;
      int bb = m >> 12, s = m & 4095;
#pragma unroll
      for (int cf = 0; cf < 4; ++cf) {
        int d = ncol + cf * 16 + (lane & 15);
        uint2 v;
        v.x = pk2bf(acc[rf][cf][0] + bv[cf], acc[rf][cf][1] + bv[cf]);
        v.y = pk2bf(acc[rf][cf][2] + bv[cf], acc[rf][cf][3] + bv[cf]);
        *(uint2*)&Vt[(size_t)(bb * 1024 + d) * 4096 + s] = v;
      }
    }
  }
}

// ---------------- flash attention v3: BQ=64, BK=256, 16 waves, LDS 2-phase pipeline ----------------
// QK: 8 kgroups x 2 qgroups, K/Q staged in LDS via global_load_lds (source-swizzled, bank-uniform reads).
// One barrier per 64-d chunk: stage(g+1) overlaps compute(g).  PV: 8 d-slices x 2 q-halves, V direct global.
__global__ __launch_bounds__(1024, 4) void flash_k(const u16* __restrict__ Qg,
    const u16* __restrict__ Kg, const u16* __restrict__ Vtg,
    float* __restrict__ Og) {
  __shared__ u16 KsBuf[2][16384];   // [2][256 keys][64 d]  64 KiB
  __shared__ u16 QsBuf[2][4096];    // [2][64 q][64 d]      16 KiB
  __shared__ u16 Ps[16896];         // [64 q][264] padded   33 KiB
  __shared__ float m2s[64], ls[64], cs[64];
  __shared__ float pmaxw[8][64], lsump[8][64];
  __shared__ int allc1;

  const int tid = threadIdx.x, lane = tid & 63, wid = tid >> 6;
  const int l15 = lane & 15, lhi = lane >> 4;
  const int bid = blockIdx.x;
  const int xcd = bid & 7;
  const int batch = xcd >> 1, qblk = (xcd & 1) * 32 + (bid >> 3);
  const u16* Qp = Qg + (size_t)(batch * 4096 + qblk * 64) * 1024;
  const u16* Kp = Kg + (size_t)batch * 4096 * 1024;
  const u16* Vp = Vtg + (size_t)batch * 1024 * 4096;
  float* Op = Og + (size_t)(batch * 4096 + qblk * 64) * 1024;

  const int kg = wid >> 1, qg = wid & 1;   // QK roles
  const int dg = wid >> 1, pvq = wid & 1;  // PV roles

  if (tid < 64) { m2s[tid] = -1e30f; ls[tid] = 0.f; }

  f32x4 O_[2][8];
#pragma unroll
  for (int qf = 0; qf < 2; ++qf)
#pragma unroll
    for (int dt = 0; dt < 8; ++dt) O_[qf][dt] = 0.f;

  // stage chunk g: K rows [tg*256, +256) cols [dcg*64, +64); Q rows [0,64) same cols.
  // LDS linear; global source pre-swizzled: LDS[row][s*8..] = G[row][(s^(row&7))*8..]
  auto STAGE = [&](int g2) {
    const int tg = g2 >> 4, dcg = g2 & 15, bb = g2 & 1;
#pragma unroll
    for (int i = 0; i < 2; ++i) {
      const int rb = wid * 16 + i * 8;
      const int row = rb + (lane >> 3), sub = lane & 7;
      const u16* src = Kp + (size_t)(tg * 256 + row) * 1024 + dcg * 64 + ((sub ^ (row & 7)) << 3);
      gl_lds16(src, &KsBuf[bb][rb * 64]);
    }
    if (wid < 8) {
      const int rb = wid * 8;
      const int row = rb + (lane >> 3), sub = lane & 7;
      const u16* src = Qp + (size_t)row * 1024 + dcg * 64 + ((sub ^ (row & 7)) << 3);
      gl_lds16(src, &QsBuf[bb][rb * 64]);
    }
  };

  STAGE(0);
  __syncthreads();

  for (int t = 0; t < 16; ++t) {
    // ---- QK^T over 256 keys, 16 chunks of 64 d ----
    f32x4 Sv[2][2];
#pragma unroll
    for (int kt = 0; kt < 2; ++kt)
#pragma unroll
      for (int qf = 0; qf < 2; ++qf) Sv[kt][qf] = 0.f;

    for (int dc = 0; dc < 16; ++dc) {
      const int g = t * 16 + dc;
      if (g + 1 < 256) STAGE(g + 1);
      const char* Kb_ = (const char*)KsBuf[g & 1];
      const char* Qb_ = (const char*)QsBuf[g & 1];
#pragma unroll
      for (int kc = 0; kc < 2; ++kc) {
        const int sub = kc * 4 + lhi;
        bf16x8 ka[2], qb[2];
#pragma unroll
        for (int kt = 0; kt < 2; ++kt) {
          const int r = kg * 32 + kt * 16 + l15;
          ka[kt] = *(const bf16x8*)(Kb_ + r * 128 + ((sub ^ (r & 7)) << 4));
        }
#pragma unroll
        for (int qf = 0; qf < 2; ++qf) {
          const int qr = qg * 32 + qf * 16 + l15;
          qb[qf] = *(const bf16x8*)(Qb_ + qr * 128 + ((sub ^ (qr & 7)) << 4));
        }
#pragma unroll
        for (int kt = 0; kt < 2; ++kt)
#pragma unroll
          for (int qf = 0; qf < 2; ++qf)
            Sv[kt][qf] = mfma16(ka[kt], qb[qf], Sv[kt][qf]);
      }
      __syncthreads();
    }

    // ---- softmax ----
    float pm[2];
#pragma unroll
    for (int qf = 0; qf < 2; ++qf) {
      float p = -1e30f;
#pragma unroll
      for (int kt = 0; kt < 2; ++kt)
#pragma unroll
        for (int r = 0; r < 4; ++r) p = fmaxf(p, Sv[kt][qf][r]);
      p = fmaxf(p, __shfl_xor(p, 16, 64));
      p = fmaxf(p, __shfl_xor(p, 32, 64));
      pm[qf] = p;
    }
    if (lane < 16) {
#pragma unroll
      for (int qf = 0; qf < 2; ++qf) pmaxw[kg][qg * 32 + qf * 16 + lane] = pm[qf];
    }
    __syncthreads();
    if (tid < 64) {
      float mt = pmaxw[0][tid];
#pragma unroll
      for (int w2 = 1; w2 < 8; ++w2) mt = fmaxf(mt, pmaxw[w2][tid]);
      mt *= FA_C32;
      float mo = m2s[tid];
      float mn = fmaxf(mo, mt);
      float c = EXP2F(mo - mn);
      cs[tid] = c;
      m2s[tid] = mn;
      int f = __all(c == 1.0f);
      if (tid == 0) allc1 = f;
    }
    __syncthreads();
    {
#pragma unroll
      for (int qf = 0; qf < 2; ++qf) {
        const int q = qg * 32 + qf * 16 + l15;
        const float mrow = m2s[q];
        float lsu = 0.f;
#pragma unroll
        for (int kt = 0; kt < 2; ++kt) {
          float p0 = EXP2F(Sv[kt][qf][0] * FA_C32 - mrow);
          float p1 = EXP2F(Sv[kt][qf][1] * FA_C32 - mrow);
          float p2 = EXP2F(Sv[kt][qf][2] * FA_C32 - mrow);
          float p3 = EXP2F(Sv[kt][qf][3] * FA_C32 - mrow);
          lsu += (p0 + p1) + (p2 + p3);
          uint2 pv;
          pv.x = pk2bf(p0, p1);
          pv.y = pk2bf(p2, p3);
          *(uint2*)((char*)Ps + q * 528 + (kg * 32 + kt * 16 + lhi * 4) * 2) = pv;
        }
        lsu += __shfl_xor(lsu, 16, 64);
        lsu += __shfl_xor(lsu, 32, 64);
        if (lane < 16) lsump[kg][qg * 32 + qf * 16 + lane] = lsu;
      }
    }
    __syncthreads();
    if (tid < 64) {
      float s = lsump[0][tid];
#pragma unroll
      for (int w2 = 1; w2 < 8; ++w2) s += lsump[w2][tid];
      ls[tid] = ls[tid] * cs[tid] + s;
    }

    // ---- PV: wave owns [32 q (pvq) x 128 d (dg)] ----
    if (!allc1) {
#pragma unroll
      for (int qf = 0; qf < 2; ++qf)
#pragma unroll
        for (int r = 0; r < 4; ++r) {
          const float c = cs[pvq * 32 + qf * 16 + lhi * 4 + r];
#pragma unroll
          for (int dt = 0; dt < 8; ++dt) O_[qf][dt][r] *= c;
        }
    }
    const int kb = t * 256;
    bf16x8 vf0[4], vf1[4];
#pragma unroll
    for (int dt = 0; dt < 4; ++dt)
      vf0[dt] = *(const bf16x8*)(Vp + (size_t)(dg * 128 + dt * 16 + l15) * 4096 + kb + lhi * 8);
#pragma unroll
    for (int kc = 0; kc < 8; ++kc) {
      bf16x8 pa[2];
#pragma unroll
      for (int qf = 0; qf < 2; ++qf)
        pa[qf] = *(const bf16x8*)((const char*)Ps + (pvq * 32 + qf * 16 + l15) * 528 + kc * 64 + lhi * 16);
#pragma unroll
      for (int dt = 0; dt < 4; ++dt)
        vf1[dt] = *(const bf16x8*)(Vp + (size_t)(dg * 128 + (dt + 4) * 16 + l15) * 4096 + kb + kc * 32 + lhi * 8);
#pragma unroll
      for (int dt = 0; dt < 4; ++dt)
#pragma unroll
        for (int qf = 0; qf < 2; ++qf) O_[qf][dt] = mfma16(pa[qf], vf0[dt], O_[qf][dt]);
      if (kc < 7) {
#pragma unroll
        for (int dt = 0; dt < 4; ++dt)
          vf0[dt] = *(const bf16x8*)(Vp + (size_t)(dg * 128 + dt * 16 + l15) * 4096 + kb + (kc + 1) * 32 + lhi * 8);
      }
#pragma unroll
      for (int dt = 0; dt < 4; ++dt)
#pragma unroll
        for (int qf = 0; qf < 2; ++qf) O_[qf][dt + 4] = mfma16(pa[qf], vf1[dt], O_[qf][dt + 4]);
    }
  }

  __syncthreads();
#pragma unroll
  for (int qf = 0; qf < 2; ++qf)
#pragma unroll
    for (int r = 0; r < 4; ++r) {
      const int row = pvq * 32 + qf * 16 + lhi * 4 + r;
      const float linv = 1.0f / ls[row];
#pragma unroll
      for (int dt = 0; dt < 8; ++dt)
        Op[(size_t)row * 1024 + dg * 128 + dt * 16 + l15] = O_[qf][dt][r] * linv;
    }
}

// ---------------- host ----------------
extern "C" void kernel_launch(void* const* d_in, const int* in_sizes, int n_in,
                              void* d_out, int out_size, void* d_ws, size_t ws_size,
                              hipStream_t stream) {
  const float* X = (const float*)d_in[0];   // [4,4096,1024]
  const float* W = (const float*)d_in[1];   // [3072,1024]
  const float* b = (const float*)d_in[2];   // [3072]
  float* out = (float*)d_out;               // [4,4096,1024] fp32
  char* ws = (char*)d_ws;
  u16* Xb = (u16*)(ws);                     // 33,554,432
  u16* Wb = (u16*)(ws + 33554432);          //  6,291,456
  u16* Qb = (u16*)(ws + 39845888);          // 33,554,432
  u16* Kb = (u16*)(ws + 73400320);          // 33,554,432
  u16* Vt = (u16*)(ws + 106954752);         // 33,554,432 (V transposed [4][1024][4096])

  cast_bf16_k<<<8192, 256, 0, stream>>>(X, Xb, 16777216 / 8);
  cast_bf16_k<<<1536, 256, 0, stream>>>(W, Wb, 3145728 / 8);
  dim3 gg(128, 24);
  gemm_qkv<<<gg, 256, 0, stream>>>(Xb, Wb, b, Qb, Kb, Vt);
  flash_k<<<256, 1024, 0, stream>>>(Qb, Kb, Vt, out);
}

// Round 4
// 739.163 us; speedup vs baseline: 1.9353x; 1.3506x over previous
//
#include <hip/hip_runtime.h>
#include <hip/hip_bf16.h>

typedef unsigned short u16;
typedef _Float16 f16x8 __attribute__((ext_vector_type(8)));
typedef float f32x4 __attribute__((ext_vector_type(4)));

#if __has_builtin(__builtin_amdgcn_exp2f)
#define EXP2F(x) __builtin_amdgcn_exp2f(x)
#else
#define EXP2F(x) exp2f(x)
#endif
#define LOG2E 1.4426950408889634f

__device__ __forceinline__ f32x4 mfma16h(f16x8 a, f16x8 b, f32x4 c) {
  return __builtin_amdgcn_mfma_f32_16x16x32_f16(a, b, c, 0, 0, 0);
}
__device__ __forceinline__ unsigned pk2h(float a, float b) {
  union { _Float16 h[2]; unsigned u; } x;
  x.h[0] = (_Float16)a; x.h[1] = (_Float16)b;
  return x.u;
}
__device__ __forceinline__ u16 h1(float a) {
  union { _Float16 h; u16 u; } x; x.h = (_Float16)a; return x.u;
}
__device__ __forceinline__ float h2f(u16 a) {
  union { u16 u; _Float16 h; } x; x.u = a; return (float)x.h;
}

typedef __attribute__((address_space(1))) const unsigned int gas_u32;
typedef __attribute__((address_space(3))) unsigned int las_u32;
__device__ __forceinline__ void gl_lds16(const u16* g, u16* l) {
  __builtin_amdgcn_global_load_lds((gas_u32*)g, (las_u32*)l, 16, 0, 0);
}

// ---------------- cast fp32 -> f16, 8 elems/thread ----------------
__global__ __launch_bounds__(256) void cast_f16_k(const float* __restrict__ src,
                                                  u16* __restrict__ dst, int n8) {
  int i = blockIdx.x * 256 + threadIdx.x;
  if (i >= n8) return;
  const float4* s4 = (const float4*)src;
  float4 a = s4[i * 2], b = s4[i * 2 + 1];
  uint4 o;
  o.x = pk2h(a.x, a.y); o.y = pk2h(a.z, a.w);
  o.z = pk2h(b.x, b.y); o.w = pk2h(b.z, b.w);
  ((uint4*)dst)[i] = o;
}

// ---------------- QKV projection GEMM (m97-structure, f16) ----------------
// C[m,n] = sum_k Xf[m,k]*Wf[n,k] + bias[n];  M=16384 N=3072 K=1024
// n in [0,1024) -> Q row-major; [1024,2048) -> K row-major; [2048,3072) -> V transposed Vt[b][d][s]
__global__ __launch_bounds__(256) void gemm_qkv(const u16* __restrict__ Xf,
    const u16* __restrict__ Wf, const float* __restrict__ bias,
    u16* __restrict__ Qo, u16* __restrict__ Ko, u16* __restrict__ Vt) {
  __shared__ u16 As[128 * 64];
  __shared__ u16 Bs[128 * 64];
  const int tid = threadIdx.x, lane = tid & 63, w = tid >> 6;
  const int m0 = blockIdx.x * 128, n0 = blockIdx.y * 128;
  const int wr = w >> 1, wc = w & 1;

  f32x4 acc[4][4];
#pragma unroll
  for (int i = 0; i < 4; ++i)
#pragma unroll
    for (int j = 0; j < 4; ++j) acc[i][j] = 0.f;

  const int srow = w * 32 + (lane >> 3);
  const int skol = (lane & 7) * 8;
  const u16* ag = Xf + (size_t)(m0 + srow) * 1024 + skol;
  const u16* bg = Wf + (size_t)(n0 + srow) * 1024 + skol;
  u16* as_l = As + (w * 4) * 512;
  u16* bs_l = Bs + (w * 4) * 512;

  for (int kt = 0; kt < 16; ++kt) {
    __syncthreads();
#pragma unroll
    for (int i = 0; i < 4; ++i) {
      gl_lds16(ag + i * 8 * 1024 + kt * 64, as_l + i * 512);
      gl_lds16(bg + i * 8 * 1024 + kt * 64, bs_l + i * 512);
    }
    __syncthreads();
#pragma unroll
    for (int kc = 0; kc < 2; ++kc) {
      f16x8 af[4], bfr[4];
#pragma unroll
      for (int rf = 0; rf < 4; ++rf)
        af[rf] = *(const f16x8*)(As + (wr * 64 + rf * 16 + (lane & 15)) * 64 + kc * 32 + (lane >> 4) * 8);
#pragma unroll
      for (int cf = 0; cf < 4; ++cf)
        bfr[cf] = *(const f16x8*)(Bs + (wc * 64 + cf * 16 + (lane & 15)) * 64 + kc * 32 + (lane >> 4) * 8);
#pragma unroll
      for (int rf = 0; rf < 4; ++rf)
#pragma unroll
        for (int cf = 0; cf < 4; ++cf)
          acc[rf][cf] = mfma16h(af[rf], bfr[cf], acc[rf][cf]);
    }
  }

  float bv[4];
#pragma unroll
  for (int cf = 0; cf < 4; ++cf) bv[cf] = bias[n0 + wc * 64 + cf * 16 + (lane & 15)];
  const int region = n0 >> 10;
  const int ncol = (n0 & 1023) + wc * 64;
  if (region < 2) {
    u16* dst = region ? Ko : Qo;
#pragma unroll
    for (int rf = 0; rf < 4; ++rf) {
      int m = m0 + wr * 64 + rf * 16 + (lane >> 4) * 4;
#pragma unroll
      for (int r = 0; r < 4; ++r)
#pragma unroll
        for (int cf = 0; cf < 4; ++cf)
          dst[(size_t)(m + r) * 1024 + ncol + cf * 16 + (lane & 15)] = h1(acc[rf][cf][r] + bv[cf]);
    }
  } else {
#pragma unroll
    for (int rf = 0; rf < 4; ++rf) {
      int m = m0 + wr * 64 + rf * 16 + (lane >> 4) * 4;
      int bb = m >> 12, s = m & 4095;
#pragma unroll
      for (int cf = 0; cf < 4; ++cf) {
        int d = ncol + cf * 16 + (lane & 15);
        uint2 v;
        v.x = pk2h(acc[rf][cf][0] + bv[cf], acc[rf][cf][1] + bv[cf]);
        v.y = pk2h(acc[rf][cf][2] + bv[cf], acc[rf][cf][3] + bv[cf]);
        *(uint2*)&Vt[(size_t)(bb * 1024 + d) * 4096 + s] = v;
      }
    }
  }
}

// ---------------- generic m97 GEMM: C = A * B^T (both row-major f16) ----------------
// EPI=0: C f16 = acc/32  (scores);  EPI=1: C f32 = acc  (output)
template <int LDA, int LDB, int KT, int EPI>
__global__ __launch_bounds__(256) void gemm_t(const u16* __restrict__ A,
    const u16* __restrict__ B, u16* __restrict__ Ch, float* __restrict__ Cf,
    const int ldc) {
  __shared__ u16 As[128 * 64];
  __shared__ u16 Bs[128 * 64];
  const int tid = threadIdx.x, lane = tid & 63, w = tid >> 6;
  const int m0 = blockIdx.x * 128, n0 = blockIdx.y * 128;
  const int wr = w >> 1, wc = w & 1;

  f32x4 acc[4][4];
#pragma unroll
  for (int i = 0; i < 4; ++i)
#pragma unroll
    for (int j = 0; j < 4; ++j) acc[i][j] = 0.f;

  const int srow = w * 32 + (lane >> 3);
  const int skol = (lane & 7) * 8;
  const u16* ag = A + (size_t)(m0 + srow) * LDA + skol;
  const u16* bg = B + (size_t)(n0 + srow) * LDB + skol;
  u16* as_l = As + (w * 4) * 512;
  u16* bs_l = Bs + (w * 4) * 512;

  for (int kt = 0; kt < KT; ++kt) {
    __syncthreads();
#pragma unroll
    for (int i = 0; i < 4; ++i) {
      gl_lds16(ag + i * 8 * LDA + kt * 64, as_l + i * 512);
      gl_lds16(bg + i * 8 * LDB + kt * 64, bs_l + i * 512);
    }
    __syncthreads();
#pragma unroll
    for (int kc = 0; kc < 2; ++kc) {
      f16x8 af[4], bfr[4];
#pragma unroll
      for (int rf = 0; rf < 4; ++rf)
        af[rf] = *(const f16x8*)(As + (wr * 64 + rf * 16 + (lane & 15)) * 64 + kc * 32 + (lane >> 4) * 8);
#pragma unroll
      for (int cf = 0; cf < 4; ++cf)
        bfr[cf] = *(const f16x8*)(Bs + (wc * 64 + cf * 16 + (lane & 15)) * 64 + kc * 32 + (lane >> 4) * 8);
#pragma unroll
      for (int rf = 0; rf < 4; ++rf)
#pragma unroll
        for (int cf = 0; cf < 4; ++cf)
          acc[rf][cf] = mfma16h(af[rf], bfr[cf], acc[rf][cf]);
    }
  }

#pragma unroll
  for (int rf = 0; rf < 4; ++rf) {
    const int m = m0 + wr * 64 + rf * 16 + (lane >> 4) * 4;
#pragma unroll
    for (int r = 0; r < 4; ++r)
#pragma unroll
      for (int cf = 0; cf < 4; ++cf) {
        const int n = n0 + wc * 64 + cf * 16 + (lane & 15);
        if (EPI == 0)
          Ch[(size_t)(m + r) * ldc + n] = h1(acc[rf][cf][r] * 0.03125f);
        else
          Cf[(size_t)(m + r) * ldc + n] = acc[rf][cf][r];
      }
  }
}

// ---------------- row softmax, in place, f16. 1 block = 1 row of 4096 ----------------
__global__ __launch_bounds__(256) void softmax_k(u16* __restrict__ S) {
  const int tid = threadIdx.x, lane = tid & 63, wid = tid >> 6;
  u16* rp = S + (size_t)blockIdx.x * 4096;
  __shared__ float redm[4], reds[4], fin[2];

  uint4 a = *(const uint4*)(rp + tid * 8);
  uint4 b = *(const uint4*)(rp + 2048 + tid * 8);
  float v[16];
  {
    union { uint4 q; u16 s[8]; } ua, ub;
    ua.q = a; ub.q = b;
#pragma unroll
    for (int i = 0; i < 8; ++i) { v[i] = h2f(ua.s[i]); v[8 + i] = h2f(ub.s[i]); }
  }
  float m = v[0];
#pragma unroll
  for (int i = 1; i < 16; ++i) m = fmaxf(m, v[i]);
#pragma unroll
  for (int o = 32; o; o >>= 1) m = fmaxf(m, __shfl_xor(m, o, 64));
  if (lane == 0) redm[wid] = m;
  __syncthreads();
  m = fmaxf(fmaxf(redm[0], redm[1]), fmaxf(redm[2], redm[3]));

  float s = 0.f;
#pragma unroll
  for (int i = 0; i < 16; ++i) { v[i] = EXP2F((v[i] - m) * LOG2E); s += v[i]; }
#pragma unroll
  for (int o = 32; o; o >>= 1) s += __shfl_xor(s, o, 64);
  if (lane == 0) reds[wid] = s;
  __syncthreads();
  const float inv = 1.0f / (reds[0] + reds[1] + reds[2] + reds[3]);

  uint4 oa, ob;
  oa.x = pk2h(v[0] * inv, v[1] * inv);   oa.y = pk2h(v[2] * inv, v[3] * inv);
  oa.z = pk2h(v[4] * inv, v[5] * inv);   oa.w = pk2h(v[6] * inv, v[7] * inv);
  ob.x = pk2h(v[8] * inv, v[9] * inv);   ob.y = pk2h(v[10] * inv, v[11] * inv);
  ob.z = pk2h(v[12] * inv, v[13] * inv); ob.w = pk2h(v[14] * inv, v[15] * inv);
  *(uint4*)(rp + tid * 8) = oa;
  *(uint4*)(rp + 2048 + tid * 8) = ob;
}

// ---------------- host ----------------
extern "C" void kernel_launch(void* const* d_in, const int* in_sizes, int n_in,
                              void* d_out, int out_size, void* d_ws, size_t ws_size,
                              hipStream_t stream) {
  const float* X = (const float*)d_in[0];   // [4,4096,1024]
  const float* W = (const float*)d_in[1];   // [3072,1024]
  const float* b = (const float*)d_in[2];   // [3072]
  float* out = (float*)d_out;               // [4,4096,1024] fp32
  char* ws = (char*)d_ws;
  // ws layout — 140,509,184 B total (identical footprint to prior rounds):
  u16* Xf = (u16*)(ws);                     // 33,554,432  X f16; DEAD after gemm_qkv -> reused as S
  u16* Wf = (u16*)(ws + 33554432);          //  6,291,456  W f16
  u16* Qf = (u16*)(ws + 39845888);          // 33,554,432  Q f16 row-major
  u16* Kf = (u16*)(ws + 73400320);          // 33,554,432  K f16 row-major
  u16* Vt = (u16*)(ws + 106954752);         // 33,554,432  V f16 transposed [4][1024][4096]
  u16* S  = Xf;                             // per-batch scores [4096][4096] f16 (33,554,432 B exact)

  cast_f16_k<<<8192, 256, 0, stream>>>(X, Xf, 16777216 / 8);
  cast_f16_k<<<1536, 256, 0, stream>>>(W, Wf, 3145728 / 8);
  dim3 gg(128, 24);
  gemm_qkv<<<gg, 256, 0, stream>>>(Xf, Wf, b, Qf, Kf, Vt);

  for (int bb = 0; bb < 4; ++bb) {
    const u16* Qb = Qf + (size_t)bb * 4096 * 1024;
    const u16* Kb = Kf + (size_t)bb * 4096 * 1024;
    const u16* Vb = Vt + (size_t)bb * 1024 * 4096;
    float* Ob = out + (size_t)bb * 4096 * 1024;
    // S = Q * K^T / 32   [4096 x 4096]
    dim3 gs(32, 32);
    gemm_t<1024, 1024, 16, 0><<<gs, 256, 0, stream>>>(Qb, Kb, S, nullptr, 4096);
    // row softmax in place
    softmax_k<<<4096, 256, 0, stream>>>(S);
    // O = P * Vt^T   [4096 x 1024]
    dim3 gp(32, 8);
    gemm_t<4096, 4096, 64, 1><<<gp, 256, 0, stream>>>(S, Vb, nullptr, Ob, 1024);
  }
}

// Round 5
// 559.269 us; speedup vs baseline: 2.5579x; 1.3217x over previous
//
#include <hip/hip_runtime.h>
#include <hip/hip_bf16.h>

typedef unsigned short u16;
typedef _Float16 f16x8 __attribute__((ext_vector_type(8)));
typedef float f32x4 __attribute__((ext_vector_type(4)));

#if __has_builtin(__builtin_amdgcn_exp2f)
#define EXP2F(x) __builtin_amdgcn_exp2f(x)
#else
#define EXP2F(x) exp2f(x)
#endif
#define LOG2E 1.4426950408889634f

__device__ __forceinline__ f32x4 mfma16h(f16x8 a, f16x8 b, f32x4 c) {
  return __builtin_amdgcn_mfma_f32_16x16x32_f16(a, b, c, 0, 0, 0);
}
__device__ __forceinline__ unsigned pk2h(float a, float b) {
  union { _Float16 h[2]; unsigned u; } x;
  x.h[0] = (_Float16)a; x.h[1] = (_Float16)b;
  return x.u;
}
__device__ __forceinline__ u16 h1(float a) {
  union { _Float16 h; u16 u; } x; x.h = (_Float16)a; return x.u;
}
__device__ __forceinline__ float h2f(u16 a) {
  union { u16 u; _Float16 h; } x; x.u = a; return (float)x.h;
}

typedef __attribute__((address_space(1))) const unsigned int gas_u32;
typedef __attribute__((address_space(3))) unsigned int las_u32;
__device__ __forceinline__ void gl_lds16(const u16* g, u16* l) {
  __builtin_amdgcn_global_load_lds((gas_u32*)g, (las_u32*)l, 16, 0, 0);
}

// ---------------- cast fp32 -> f16, 8 elems/thread ----------------
__global__ __launch_bounds__(256) void cast_f16_k(const float* __restrict__ src,
                                                  u16* __restrict__ dst, int n8) {
  int i = blockIdx.x * 256 + threadIdx.x;
  if (i >= n8) return;
  const float4* s4 = (const float4*)src;
  float4 a = s4[i * 2], b = s4[i * 2 + 1];
  uint4 o;
  o.x = pk2h(a.x, a.y); o.y = pk2h(a.z, a.w);
  o.z = pk2h(b.x, b.y); o.w = pk2h(b.z, b.w);
  ((uint4*)dst)[i] = o;
}

// ---------------- QKV projection GEMM (m97-structure, f16) ----------------
__global__ __launch_bounds__(256) void gemm_qkv(const u16* __restrict__ Xf,
    const u16* __restrict__ Wf, const float* __restrict__ bias,
    u16* __restrict__ Qo, u16* __restrict__ Ko, u16* __restrict__ Vt) {
  __shared__ u16 As[128 * 64];
  __shared__ u16 Bs[128 * 64];
  const int tid = threadIdx.x, lane = tid & 63, w = tid >> 6;
  const int m0 = blockIdx.x * 128, n0 = blockIdx.y * 128;
  const int wr = w >> 1, wc = w & 1;

  f32x4 acc[4][4];
#pragma unroll
  for (int i = 0; i < 4; ++i)
#pragma unroll
    for (int j = 0; j < 4; ++j) acc[i][j] = 0.f;

  const int srow = w * 32 + (lane >> 3);
  const int skol = (lane & 7) * 8;
  const u16* ag = Xf + (size_t)(m0 + srow) * 1024 + skol;
  const u16* bg = Wf + (size_t)(n0 + srow) * 1024 + skol;
  u16* as_l = As + (w * 4) * 512;
  u16* bs_l = Bs + (w * 4) * 512;

  for (int kt = 0; kt < 16; ++kt) {
    __syncthreads();
#pragma unroll
    for (int i = 0; i < 4; ++i) {
      gl_lds16(ag + i * 8 * 1024 + kt * 64, as_l + i * 512);
      gl_lds16(bg + i * 8 * 1024 + kt * 64, bs_l + i * 512);
    }
    __syncthreads();
#pragma unroll
    for (int kc = 0; kc < 2; ++kc) {
      f16x8 af[4], bfr[4];
#pragma unroll
      for (int rf = 0; rf < 4; ++rf)
        af[rf] = *(const f16x8*)(As + (wr * 64 + rf * 16 + (lane & 15)) * 64 + kc * 32 + (lane >> 4) * 8);
#pragma unroll
      for (int cf = 0; cf < 4; ++cf)
        bfr[cf] = *(const f16x8*)(Bs + (wc * 64 + cf * 16 + (lane & 15)) * 64 + kc * 32 + (lane >> 4) * 8);
#pragma unroll
      for (int rf = 0; rf < 4; ++rf)
#pragma unroll
        for (int cf = 0; cf < 4; ++cf)
          acc[rf][cf] = mfma16h(af[rf], bfr[cf], acc[rf][cf]);
    }
  }

  float bv[4];
#pragma unroll
  for (int cf = 0; cf < 4; ++cf) bv[cf] = bias[n0 + wc * 64 + cf * 16 + (lane & 15)];
  const int region = n0 >> 10;
  const int ncol = (n0 & 1023) + wc * 64;
  if (region < 2) {
    u16* dst = region ? Ko : Qo;
#pragma unroll
    for (int rf = 0; rf < 4; ++rf) {
      int m = m0 + wr * 64 + rf * 16 + (lane >> 4) * 4;
#pragma unroll
      for (int r = 0; r < 4; ++r)
#pragma unroll
        for (int cf = 0; cf < 4; ++cf)
          dst[(size_t)(m + r) * 1024 + ncol + cf * 16 + (lane & 15)] = h1(acc[rf][cf][r] + bv[cf]);
    }
  } else {
#pragma unroll
    for (int rf = 0; rf < 4; ++rf) {
      int m = m0 + wr * 64 + rf * 16 + (lane >> 4) * 4;
      int bb = m >> 12, s = m & 4095;
#pragma unroll
      for (int cf = 0; cf < 4; ++cf) {
        int d = ncol + cf * 16 + (lane & 15);
        uint2 v;
        v.x = pk2h(acc[rf][cf][0] + bv[cf], acc[rf][cf][1] + bv[cf]);
        v.y = pk2h(acc[rf][cf][2] + bv[cf], acc[rf][cf][3] + bv[cf]);
        *(uint2*)&Vt[(size_t)(bb * 1024 + d) * 4096 + s] = v;
      }
    }
  }
}

// ---------------- generic m97 GEMM, z-batched: C = A * B^T (row-major f16) ----------------
// EPI=0: C f16 = acc/32  (scores);  EPI=1: C f32 = acc  (output)
template <int LDA, int LDB, int KT, int EPI>
__global__ __launch_bounds__(256) void gemm_t(const u16* __restrict__ A,
    const u16* __restrict__ B, u16* __restrict__ Ch, float* __restrict__ Cf,
    const int ldc, const size_t strA, const size_t strB, const size_t strC) {
  __shared__ u16 As[128 * 64];
  __shared__ u16 Bs[128 * 64];
  const int tid = threadIdx.x, lane = tid & 63, w = tid >> 6;
  const int m0 = blockIdx.x * 128, n0 = blockIdx.y * 128;
  const int bz = blockIdx.z;
  A += (size_t)bz * strA;
  B += (size_t)bz * strB;
  const int wr = w >> 1, wc = w & 1;

  f32x4 acc[4][4];
#pragma unroll
  for (int i = 0; i < 4; ++i)
#pragma unroll
    for (int j = 0; j < 4; ++j) acc[i][j] = 0.f;

  const int srow = w * 32 + (lane >> 3);
  const int skol = (lane & 7) * 8;
  const u16* ag = A + (size_t)(m0 + srow) * LDA + skol;
  const u16* bg = B + (size_t)(n0 + srow) * LDB + skol;
  u16* as_l = As + (w * 4) * 512;
  u16* bs_l = Bs + (w * 4) * 512;

  for (int kt = 0; kt < KT; ++kt) {
    __syncthreads();
#pragma unroll
    for (int i = 0; i < 4; ++i) {
      gl_lds16(ag + i * 8 * LDA + kt * 64, as_l + i * 512);
      gl_lds16(bg + i * 8 * LDB + kt * 64, bs_l + i * 512);
    }
    __syncthreads();
#pragma unroll
    for (int kc = 0; kc < 2; ++kc) {
      f16x8 af[4], bfr[4];
#pragma unroll
      for (int rf = 0; rf < 4; ++rf)
        af[rf] = *(const f16x8*)(As + (wr * 64 + rf * 16 + (lane & 15)) * 64 + kc * 32 + (lane >> 4) * 8);
#pragma unroll
      for (int cf = 0; cf < 4; ++cf)
        bfr[cf] = *(const f16x8*)(Bs + (wc * 64 + cf * 16 + (lane & 15)) * 64 + kc * 32 + (lane >> 4) * 8);
#pragma unroll
      for (int rf = 0; rf < 4; ++rf)
#pragma unroll
        for (int cf = 0; cf < 4; ++cf)
          acc[rf][cf] = mfma16h(af[rf], bfr[cf], acc[rf][cf]);
    }
  }

#pragma unroll
  for (int rf = 0; rf < 4; ++rf) {
    const int m = m0 + wr * 64 + rf * 16 + (lane >> 4) * 4;
#pragma unroll
    for (int r = 0; r < 4; ++r)
#pragma unroll
      for (int cf = 0; cf < 4; ++cf) {
        const int n = n0 + wc * 64 + cf * 16 + (lane & 15);
        if (EPI == 0)
          Ch[(size_t)bz * strC + (size_t)(m + r) * ldc + n] = h1(acc[rf][cf][r] * 0.03125f);
        else
          Cf[(size_t)bz * strC + (size_t)(m + r) * ldc + n] = acc[rf][cf][r];
      }
  }
}

// ---------------- row softmax, in place, f16. 1 block = 1 row of 4096 ----------------
__global__ __launch_bounds__(256) void softmax_k(u16* __restrict__ S) {
  const int tid = threadIdx.x, lane = tid & 63, wid = tid >> 6;
  u16* rp = S + (size_t)blockIdx.x * 4096;
  __shared__ float redm[4], reds[4];

  uint4 a = *(const uint4*)(rp + tid * 8);
  uint4 b = *(const uint4*)(rp + 2048 + tid * 8);
  float v[16];
  {
    union { uint4 q; u16 s[8]; } ua, ub;
    ua.q = a; ub.q = b;
#pragma unroll
    for (int i = 0; i < 8; ++i) { v[i] = h2f(ua.s[i]); v[8 + i] = h2f(ub.s[i]); }
  }
  float m = v[0];
#pragma unroll
  for (int i = 1; i < 16; ++i) m = fmaxf(m, v[i]);
#pragma unroll
  for (int o = 32; o; o >>= 1) m = fmaxf(m, __shfl_xor(m, o, 64));
  if (lane == 0) redm[wid] = m;
  __syncthreads();
  m = fmaxf(fmaxf(redm[0], redm[1]), fmaxf(redm[2], redm[3]));

  float s = 0.f;
#pragma unroll
  for (int i = 0; i < 16; ++i) { v[i] = EXP2F((v[i] - m) * LOG2E); s += v[i]; }
#pragma unroll
  for (int o = 32; o; o >>= 1) s += __shfl_xor(s, o, 64);
  if (lane == 0) reds[wid] = s;
  __syncthreads();
  const float inv = 1.0f / (reds[0] + reds[1] + reds[2] + reds[3]);

  uint4 oa, ob;
  oa.x = pk2h(v[0] * inv, v[1] * inv);   oa.y = pk2h(v[2] * inv, v[3] * inv);
  oa.z = pk2h(v[4] * inv, v[5] * inv);   oa.w = pk2h(v[6] * inv, v[7] * inv);
  ob.x = pk2h(v[8] * inv, v[9] * inv);   ob.y = pk2h(v[10] * inv, v[11] * inv);
  ob.z = pk2h(v[12] * inv, v[13] * inv); ob.w = pk2h(v[14] * inv, v[15] * inv);
  *(uint4*)(rp + tid * 8) = oa;
  *(uint4*)(rp + 2048 + tid * 8) = ob;
}

// ---------------- host ----------------
extern "C" void kernel_launch(void* const* d_in, const int* in_sizes, int n_in,
                              void* d_out, int out_size, void* d_ws, size_t ws_size,
                              hipStream_t stream) {
  const float* X = (const float*)d_in[0];   // [4,4096,1024]
  const float* W = (const float*)d_in[1];   // [3072,1024]
  const float* b = (const float*)d_in[2];   // [3072]
  float* out = (float*)d_out;               // [4,4096,1024] fp32
  char* ws = (char*)d_ws;

  // Batch-group size NB tiered by available workspace (runtime guard; NB=1 is
  // the known-good 140,509,184-B layout from round 4).
  const size_t SB = (size_t)4096 * 4096 * 2;          // S bytes per batch (33.55 MB)
  const size_t QB = (size_t)4096 * 1024 * 2;          // Q/K/V bytes per batch
  const size_t WFB = (size_t)3072 * 1024 * 2;         // Wf bytes
  int NB = 1;
  if (ws_size >= 4 * SB + WFB + 12 * QB) NB = 4;      // 241,172,480
  else if (ws_size >= 2 * SB + WFB + 12 * QB) NB = 2; // 174,063,616

  // layout: [S region: NB*SB (Xf overlaid at its base; dead after gemm_qkv)]
  //         [Wf][Qf][Kf][Vt]
  u16* S  = (u16*)(ws);
  u16* Xf = (u16*)(ws);                               // overlay, 33.55 MB <= NB*SB
  u16* Wf = (u16*)(ws + (size_t)NB * SB);
  u16* Qf = (u16*)(ws + (size_t)NB * SB + WFB);
  u16* Kf = (u16*)(ws + (size_t)NB * SB + WFB + 4 * QB);
  u16* Vt = (u16*)(ws + (size_t)NB * SB + WFB + 8 * QB);

  cast_f16_k<<<8192, 256, 0, stream>>>(X, Xf, 16777216 / 8);
  cast_f16_k<<<1536, 256, 0, stream>>>(W, Wf, 3145728 / 8);
  dim3 gg(128, 24);
  gemm_qkv<<<gg, 256, 0, stream>>>(Xf, Wf, b, Qf, Kf, Vt);

  const size_t strQ = (size_t)4096 * 1024;   // elements
  const size_t strS = (size_t)4096 * 4096;
  const size_t strV = (size_t)1024 * 4096;
  for (int g = 0; g < 4; g += NB) {
    const u16* Qg = Qf + (size_t)g * strQ;
    const u16* Kg = Kf + (size_t)g * strQ;
    const u16* Vg = Vt + (size_t)g * strV;
    float* Og = out + (size_t)g * strQ;
    // S[z] = Q[z] * K[z]^T / 32   [4096 x 4096] x NB
    dim3 gs(32, 32, NB);
    gemm_t<1024, 1024, 16, 0><<<gs, 256, 0, stream>>>(Qg, Kg, S, nullptr, 4096,
                                                      strQ, strQ, strS);
    // row softmax in place over NB batches
    softmax_k<<<4096 * NB, 256, 0, stream>>>(S);
    // O[z] = P[z] * Vt[z]^T   [4096 x 1024] x NB
    dim3 gp(32, 8, NB);
    gemm_t<4096, 4096, 64, 1><<<gp, 256, 0, stream>>>(S, Vg, nullptr, Og, 1024,
                                                      strS, strV, strQ);
  }
}

// Round 6
// 532.342 us; speedup vs baseline: 2.6872x; 1.0506x over previous
//
#include <hip/hip_runtime.h>
#include <hip/hip_bf16.h>

typedef unsigned short u16;
typedef _Float16 f16x8 __attribute__((ext_vector_type(8)));
typedef float f32x4 __attribute__((ext_vector_type(4)));

#if __has_builtin(__builtin_amdgcn_exp2f)
#define EXP2F(x) __builtin_amdgcn_exp2f(x)
#else
#define EXP2F(x) exp2f(x)
#endif
#define LOG2E 1.4426950408889634f

__device__ __forceinline__ f32x4 mfma16h(f16x8 a, f16x8 b, f32x4 c) {
  return __builtin_amdgcn_mfma_f32_16x16x32_f16(a, b, c, 0, 0, 0);
}
__device__ __forceinline__ unsigned pk2h(float a, float b) {
  union { _Float16 h[2]; unsigned u; } x;
  x.h[0] = (_Float16)a; x.h[1] = (_Float16)b;
  return x.u;
}
__device__ __forceinline__ u16 h1(float a) {
  union { _Float16 h; u16 u; } x; x.h = (_Float16)a; return x.u;
}
__device__ __forceinline__ float h2f(u16 a) {
  union { u16 u; _Float16 h; } x; x.u = a; return (float)x.h;
}

typedef __attribute__((address_space(1))) const unsigned int gas_u32;
typedef __attribute__((address_space(3))) unsigned int las_u32;
__device__ __forceinline__ void gl_lds16(const u16* g, u16* l) {
  __builtin_amdgcn_global_load_lds((gas_u32*)g, (las_u32*)l, 16, 0, 0);
}

// ---------------- cast fp32 -> f16, 8 elems/thread ----------------
__global__ __launch_bounds__(256) void cast_f16_k(const float* __restrict__ src,
                                                  u16* __restrict__ dst, int n8) {
  int i = blockIdx.x * 256 + threadIdx.x;
  if (i >= n8) return;
  const float4* s4 = (const float4*)src;
  float4 a = s4[i * 2], b = s4[i * 2 + 1];
  uint4 o;
  o.x = pk2h(a.x, a.y); o.y = pk2h(a.z, a.w);
  o.z = pk2h(b.x, b.y); o.w = pk2h(b.z, b.w);
  ((uint4*)dst)[i] = o;
}

// =================================================================
// 256x256-tile GEMM, BK=32, 8 waves, ring-4 LDS pipeline (128 KiB),
// one raw s_barrier per K-step, counted vmcnt (never 0 in main loop).
// C = A * B^T, A[M][K_], B[N][K_] row-major f16.
//   EPI=0: D0 f16 = acc/32 (scores)   EPI=1: Df f32 = acc
//   EPI=2: QKV scatter: n<1024 -> D0 (Q), <2048 -> D1 (K), else D2 = Vt[b][d][s]
// Race ledger:
//   RAW: iter kt: vmcnt(8) waits own tile-kt loads; barrier publishes all waves'.
//   WAR: STAGE(kt+3) (slot (kt-1)&3) issued AFTER barrier; tile kt-1 reads
//        completed in every wave before it reached this barrier (MFMA data deps).
// =================================================================
template <int K_, int EPI>
__global__ __launch_bounds__(512, 2) void gemm256(
    const u16* __restrict__ A, const u16* __restrict__ B,
    const float* __restrict__ bias, u16* __restrict__ D0, u16* __restrict__ D1,
    u16* __restrict__ D2, float* __restrict__ Df, const int ldc,
    const size_t strA, const size_t strB, const size_t strC) {
  constexpr int KT = K_ / 32;
  static_assert(KT >= 4, "need >=4 K-tiles");
  __shared__ u16 As[4][8192];   // [slot][256 rows][32 k]  64 KiB
  __shared__ u16 Bs[4][8192];   // 64 KiB

  const int tid = threadIdx.x, lane = tid & 63, wid = tid >> 6;
  const int l15 = lane & 15, lhi = lane >> 4;
  const int m0 = blockIdx.x * 256, n0 = blockIdx.y * 256;
  const int bz = blockIdx.z;
  const int wr = wid >> 2, wc = wid & 3;     // wave tile: rows [wr*128,+128) cols [wc*64,+64)

  const u16* Ag = A + (size_t)bz * strA;
  const u16* Bg = B + (size_t)bz * strB;

  // staging geometry: wave w stages rows [w*32,+32) of A and of B per tile.
  // chunk i (i=0,1): rows w*32+i*16 + (lane>>2); source col pre-swizzled
  // (T2 both-sides): LDS[row][sub] <- G[row][sub ^ (row&3)] (16B units).
  const int rl = lane >> 2, sub = lane & 3;
  const int scol = ((sub ^ (rl & 3)) << 3);  // u16 offset in row
  const int r0 = wid * 32;
  const size_t abase = (size_t)(m0 + r0 + rl) * K_ + scol;
  const size_t bbase = (size_t)(n0 + r0 + rl) * K_ + scol;

  f32x4 acc[8][4];
#pragma unroll
  for (int i = 0; i < 8; ++i)
#pragma unroll
    for (int j = 0; j < 4; ++j) acc[i][j] = 0.f;

  auto STAGE = [&](int t) {
    const int sl = t & 3;
#pragma unroll
    for (int i = 0; i < 2; ++i)
      gl_lds16(Ag + abase + (size_t)i * (16 * K_) + t * 32, &As[sl][(r0 + i * 16) * 32]);
#pragma unroll
    for (int i = 0; i < 2; ++i)
      gl_lds16(Bg + bbase + (size_t)i * (16 * K_) + t * 32, &Bs[sl][(r0 + i * 16) * 32]);
  };

  STAGE(0); STAGE(1); STAGE(2);              // 12 loads in flight

  const int rswz = ((lhi ^ (l15 & 3)) << 4); // read-side XOR (bytes)

  for (int kt = 0; kt < KT; ++kt) {
    if (kt < KT - 2)       asm volatile("s_waitcnt vmcnt(8)" ::: "memory");
    else if (kt == KT - 2) asm volatile("s_waitcnt vmcnt(4)" ::: "memory");
    else                   asm volatile("s_waitcnt vmcnt(0)" ::: "memory");
    __builtin_amdgcn_s_barrier();
    asm volatile("" ::: "memory");
    if (kt + 3 < KT) STAGE(kt + 3);

    const char* Ab = (const char*)As[kt & 3];
    const char* Bb = (const char*)Bs[kt & 3];
    f16x8 af[8], bf_[4];
#pragma unroll
    for (int rf = 0; rf < 8; ++rf)
      af[rf] = *(const f16x8*)(Ab + (wr * 128 + rf * 16 + l15) * 64 + rswz);
#pragma unroll
    for (int cf = 0; cf < 4; ++cf)
      bf_[cf] = *(const f16x8*)(Bb + (wc * 64 + cf * 16 + l15) * 64 + rswz);
#pragma unroll
    for (int rf = 0; rf < 8; ++rf)
#pragma unroll
      for (int cf = 0; cf < 4; ++cf)
        acc[rf][cf] = mfma16h(af[rf], bf_[cf], acc[rf][cf]);
  }

  // ---------------- epilogues ----------------
  if (EPI == 2) {
    float bv[4];
#pragma unroll
    for (int cf = 0; cf < 4; ++cf) bv[cf] = bias[n0 + wc * 64 + cf * 16 + l15];
    const int region = n0 >> 10;             // 256-tile never straddles 1024-boundary
    const int ncol0 = (n0 & 1023) + wc * 64;
    if (region < 2) {
      u16* dst = region ? D1 : D0;
#pragma unroll
      for (int rf = 0; rf < 8; ++rf) {
        const int m = m0 + wr * 128 + rf * 16 + lhi * 4;
#pragma unroll
        for (int r = 0; r < 4; ++r)
#pragma unroll
          for (int cf = 0; cf < 4; ++cf)
            dst[(size_t)(m + r) * 1024 + ncol0 + cf * 16 + l15] = h1(acc[rf][cf][r] + bv[cf]);
      }
    } else {
#pragma unroll
      for (int rf = 0; rf < 8; ++rf) {
        const int m = m0 + wr * 128 + rf * 16 + lhi * 4;
        const int bb = m >> 12, s = m & 4095;
#pragma unroll
        for (int cf = 0; cf < 4; ++cf) {
          const int d = ncol0 + cf * 16 + l15;
          uint2 v;
          v.x = pk2h(acc[rf][cf][0] + bv[cf], acc[rf][cf][1] + bv[cf]);
          v.y = pk2h(acc[rf][cf][2] + bv[cf], acc[rf][cf][3] + bv[cf]);
          *(uint2*)&D2[(size_t)(bb * 1024 + d) * 4096 + s] = v;
        }
      }
    }
  } else if (EPI == 0) {
#pragma unroll
    for (int rf = 0; rf < 8; ++rf) {
      const int m = m0 + wr * 128 + rf * 16 + lhi * 4;
#pragma unroll
      for (int r = 0; r < 4; ++r)
#pragma unroll
        for (int cf = 0; cf < 4; ++cf) {
          const int n = n0 + wc * 64 + cf * 16 + l15;
          D0[(size_t)bz * strC + (size_t)(m + r) * ldc + n] = h1(acc[rf][cf][r] * 0.03125f);
        }
    }
  } else {
#pragma unroll
    for (int rf = 0; rf < 8; ++rf) {
      const int m = m0 + wr * 128 + rf * 16 + lhi * 4;
#pragma unroll
      for (int r = 0; r < 4; ++r)
#pragma unroll
        for (int cf = 0; cf < 4; ++cf) {
          const int n = n0 + wc * 64 + cf * 16 + l15;
          Df[(size_t)bz * strC + (size_t)(m + r) * ldc + n] = acc[rf][cf][r];
        }
    }
  }
}

// ---------------- row softmax, in place, f16. 1 block = 1 row of 4096 ----------------
__global__ __launch_bounds__(256) void softmax_k(u16* __restrict__ S) {
  const int tid = threadIdx.x, lane = tid & 63, wid = tid >> 6;
  u16* rp = S + (size_t)blockIdx.x * 4096;
  __shared__ float redm[4], reds[4];

  uint4 a = *(const uint4*)(rp + tid * 8);
  uint4 b = *(const uint4*)(rp + 2048 + tid * 8);
  float v[16];
  {
    union { uint4 q; u16 s[8]; } ua, ub;
    ua.q = a; ub.q = b;
#pragma unroll
    for (int i = 0; i < 8; ++i) { v[i] = h2f(ua.s[i]); v[8 + i] = h2f(ub.s[i]); }
  }
  float m = v[0];
#pragma unroll
  for (int i = 1; i < 16; ++i) m = fmaxf(m, v[i]);
#pragma unroll
  for (int o = 32; o; o >>= 1) m = fmaxf(m, __shfl_xor(m, o, 64));
  if (lane == 0) redm[wid] = m;
  __syncthreads();
  m = fmaxf(fmaxf(redm[0], redm[1]), fmaxf(redm[2], redm[3]));

  float s = 0.f;
#pragma unroll
  for (int i = 0; i < 16; ++i) { v[i] = EXP2F((v[i] - m) * LOG2E); s += v[i]; }
#pragma unroll
  for (int o = 32; o; o >>= 1) s += __shfl_xor(s, o, 64);
  if (lane == 0) reds[wid] = s;
  __syncthreads();
  const float inv = 1.0f / (reds[0] + reds[1] + reds[2] + reds[3]);

  uint4 oa, ob;
  oa.x = pk2h(v[0] * inv, v[1] * inv);   oa.y = pk2h(v[2] * inv, v[3] * inv);
  oa.z = pk2h(v[4] * inv, v[5] * inv);   oa.w = pk2h(v[6] * inv, v[7] * inv);
  ob.x = pk2h(v[8] * inv, v[9] * inv);   ob.y = pk2h(v[10] * inv, v[11] * inv);
  ob.z = pk2h(v[12] * inv, v[13] * inv); ob.w = pk2h(v[14] * inv, v[15] * inv);
  *(uint4*)(rp + tid * 8) = oa;
  *(uint4*)(rp + 2048 + tid * 8) = ob;
}

// ---------------- host ----------------
extern "C" void kernel_launch(void* const* d_in, const int* in_sizes, int n_in,
                              void* d_out, int out_size, void* d_ws, size_t ws_size,
                              hipStream_t stream) {
  const float* X = (const float*)d_in[0];   // [4,4096,1024]
  const float* W = (const float*)d_in[1];   // [3072,1024]
  const float* b = (const float*)d_in[2];   // [3072]
  float* out = (float*)d_out;               // [4,4096,1024] fp32
  char* ws = (char*)d_ws;

  const size_t SB = (size_t)4096 * 4096 * 2;          // S bytes per batch
  const size_t QB = (size_t)4096 * 1024 * 2;
  const size_t WFB = (size_t)3072 * 1024 * 2;
  int NB = 1;
  if (ws_size >= 4 * SB + WFB + 12 * QB) NB = 4;
  else if (ws_size >= 2 * SB + WFB + 12 * QB) NB = 2;

  u16* S  = (u16*)(ws);
  u16* Xf = (u16*)(ws);                               // overlay; dead after gemm_qkv
  u16* Wf = (u16*)(ws + (size_t)NB * SB);
  u16* Qf = (u16*)(ws + (size_t)NB * SB + WFB);
  u16* Kf = (u16*)(ws + (size_t)NB * SB + WFB + 4 * QB);
  u16* Vt = (u16*)(ws + (size_t)NB * SB + WFB + 8 * QB);

  cast_f16_k<<<8192, 256, 0, stream>>>(X, Xf, 16777216 / 8);
  cast_f16_k<<<1536, 256, 0, stream>>>(W, Wf, 3145728 / 8);

  // QKV projection: M=16384, N=3072, K=1024
  gemm256<1024, 2><<<dim3(64, 12, 1), 512, 0, stream>>>(
      Xf, Wf, b, Qf, Kf, Vt, nullptr, 0, 0, 0, 0);

  const size_t strQ = (size_t)4096 * 1024;
  const size_t strS = (size_t)4096 * 4096;
  const size_t strV = (size_t)1024 * 4096;
  for (int g = 0; g < 4; g += NB) {
    const u16* Qg = Qf + (size_t)g * strQ;
    const u16* Kg = Kf + (size_t)g * strQ;
    const u16* Vg = Vt + (size_t)g * strV;
    float* Og = out + (size_t)g * strQ;
    // S = Q K^T / 32  [4096x4096] x NB
    gemm256<1024, 0><<<dim3(16, 16, NB), 512, 0, stream>>>(
        Qg, Kg, nullptr, S, nullptr, nullptr, nullptr, 4096, strQ, strQ, strS);
    softmax_k<<<4096 * NB, 256, 0, stream>>>(S);
    // O = P Vt^T  [4096x1024] x NB
    gemm256<4096, 1><<<dim3(16, 4, NB), 512, 0, stream>>>(
        S, Vg, nullptr, nullptr, nullptr, nullptr, Og, 1024, strS, strV, strQ);
  }
}

// Round 9
// 447.201 us; speedup vs baseline: 3.1989x; 1.1904x over previous
//
#include <hip/hip_runtime.h>
#include <hip/hip_bf16.h>

typedef unsigned short u16;
typedef _Float16 f16x8 __attribute__((ext_vector_type(8)));
typedef float f32x4 __attribute__((ext_vector_type(4)));

#if __has_builtin(__builtin_amdgcn_exp2f)
#define EXP2F(x) __builtin_amdgcn_exp2f(x)
#else
#define EXP2F(x) exp2f(x)
#endif
#define LOG2E 1.4426950408889634f

__device__ __forceinline__ f32x4 mfma16h(f16x8 a, f16x8 b, f32x4 c) {
  return __builtin_amdgcn_mfma_f32_16x16x32_f16(a, b, c, 0, 0, 0);
}
__device__ __forceinline__ unsigned pk2h(float a, float b) {
  union { _Float16 h[2]; unsigned u; } x;
  x.h[0] = (_Float16)a; x.h[1] = (_Float16)b;
  return x.u;
}
__device__ __forceinline__ u16 h1(float a) {
  union { _Float16 h; u16 u; } x; x.h = (_Float16)a; return x.u;
}
__device__ __forceinline__ float h2f(u16 a) {
  union { u16 u; _Float16 h; } x; x.u = a; return (float)x.h;
}

typedef __attribute__((address_space(1))) const unsigned int gas_u32;
typedef __attribute__((address_space(3))) unsigned int las_u32;
__device__ __forceinline__ void gl_lds16(const u16* g, u16* l) {
  __builtin_amdgcn_global_load_lds((gas_u32*)g, (las_u32*)l, 16, 0, 0);
}

// ---------------- cast fp32 -> f16, 8 elems/thread ----------------
__global__ __launch_bounds__(256) void cast_f16_k(const float* __restrict__ src,
                                                  u16* __restrict__ dst, int n8) {
  int i = blockIdx.x * 256 + threadIdx.x;
  if (i >= n8) return;
  const float4* s4 = (const float4*)src;
  float4 a = s4[i * 2], b = s4[i * 2 + 1];
  uint4 o;
  o.x = pk2h(a.x, a.y); o.y = pk2h(a.z, a.w);
  o.z = pk2h(b.x, b.y); o.w = pk2h(b.z, b.w);
  ((uint4*)dst)[i] = o;
}

// =================================================================
// 8-phase GEMM: BM=BN=256, BK=64, 8 waves (2Mx4N), acc 8x4.
// 2 K-tiles/iteration (dbuf0 = tile 2i, dbuf1 = tile 2i+1), 4 phases/tile.
// QUARTER-GRANULARITY staging (the round-7/8 bug fix): each stage unit is a
// 64-row quarter = exactly one read-subblock, staged strictly AFTER its last
// LDS read phase:
//   ph0: read a0(Aq0/q2), b0    stages: none
//   ph1: read b1                stages: A q0,q2 of tile+2 (a0 read ph0)
//   ph2: read a1(Aq1/q3)        stages: B q0..q3 of tile+2 (B read ph0/ph1)
//   ph3: (regs only)            stages: A q1,q3 of tile+2 (a1 read ph2)
// Phase = { ds_read | stage | BAR | lgkmcnt(0)+schedbar | prio1 16xMFMA prio0
//           | schedbar | [vmcnt at ph3/ph7] | BAR }.
// Reads of a stage's target are serviced by the explicit lgkmcnt(0) BEFORE
// that phase's closing barrier; the stage is issued after it -> WAR-safe
// regardless of compiler scheduling. 8 loads/wave/tile; vmcnt(8) at ph3/ph7
// drains exactly the next-needed tile (FIFO); vmcnt(0) only in last iter.
//   EPI=0: D0 f16 = acc/32   EPI=1: Df f32 = acc
//   EPI=2: QKV scatter (Q,K row-major; V -> Vt[b][d][s])
// =================================================================
template <int K_, int EPI>
__global__ __launch_bounds__(512, 2) void gemm8p(
    const u16* __restrict__ A, const u16* __restrict__ B,
    const float* __restrict__ bias, u16* __restrict__ D0, u16* __restrict__ D1,
    u16* __restrict__ D2, float* __restrict__ Df, const int ldc,
    const size_t strA, const size_t strB, const size_t strC) {
  constexpr int NT = K_ / 64;
  static_assert(NT >= 4 && (NT % 2) == 0, "need even NT >= 4");
  __shared__ __align__(16) u16 As[2][2][128 * 64];   // [dbuf][M-half]
  __shared__ __align__(16) u16 Bs[2][2][128 * 64];   // [dbuf][N-half]

  const int tid = threadIdx.x, lane = tid & 63, wid = tid >> 6;
  const int l15 = lane & 15, lhi = lane >> 4;
  const int m0 = blockIdx.x * 256, n0 = blockIdx.y * 256;
  const int wm = wid >> 2, wn = wid & 3;
  const u16* Ag = A + (size_t)blockIdx.z * strA;
  const u16* Bg = B + (size_t)blockIdx.z * strB;

  const int srow8 = lane >> 3;              // LDS row & 7 for this lane's 16B
  const int sblk = (lane & 7) ^ srow8;      // source block XOR (T2 both-sides)

// one 64-row quarter: 1 global_load_lds per wave (8 rows/wave)
#define STAGE_Q(BUF, G, GROW0, ST)                                        \
  gl_lds16((G) + (size_t)((GROW0) + wid * 8 + srow8) * K_ +               \
               (ST) * 64 + sblk * 8,                                      \
           (BUF) + (wid * 8) * 64)

#define BAR()                                                             \
  asm volatile("" ::: "memory");                                          \
  __builtin_amdgcn_s_barrier();                                           \
  asm volatile("" ::: "memory")

#define LGKM0()                                                           \
  asm volatile("s_waitcnt lgkmcnt(0)" ::: "memory");                      \
  __builtin_amdgcn_sched_barrier(0)

#define SB0() __builtin_amdgcn_sched_barrier(0)
#define VMC8() asm volatile("s_waitcnt vmcnt(8)" ::: "memory")
#define VMC0() asm volatile("s_waitcnt vmcnt(0)" ::: "memory")

#define RD_A(DST, PB, MH)                                                 \
  _Pragma("unroll") for (int mf = 0; mf < 4; ++mf)                        \
  _Pragma("unroll") for (int ks = 0; ks < 2; ++ks)                        \
    DST[mf][ks] = *(const f16x8*)((PB) + ((MH) * 64 + mf * 16 + l15) * 64 \
                                  + (((ks * 4 + lhi) ^ (l15 & 7)) * 8));

#define RD_B(DST, PB, BO, NH)                                             \
  _Pragma("unroll") for (int nf = 0; nf < 2; ++nf)                        \
  _Pragma("unroll") for (int ks = 0; ks < 2; ++ks)                        \
    DST[nf][ks] = *(const f16x8*)((PB) + ((BO) + (NH) * 32 + nf * 16 + l15) * 64 \
                                  + (((ks * 4 + lhi) ^ (l15 & 7)) * 8));

#define MM(AV, BV, MB, NB2)                                               \
  __builtin_amdgcn_s_setprio(1);                                          \
  _Pragma("unroll") for (int mf = 0; mf < 4; ++mf)                        \
  _Pragma("unroll") for (int nf = 0; nf < 2; ++nf)                        \
  _Pragma("unroll") for (int ks = 0; ks < 2; ++ks)                        \
    acc[(MB) * 4 + mf][(NB2) * 2 + nf] =                                  \
        mfma16h(AV[mf][ks], BV[nf][ks], acc[(MB) * 4 + mf][(NB2) * 2 + nf]); \
  __builtin_amdgcn_s_setprio(0);

  f32x4 acc[8][4];
#pragma unroll
  for (int i = 0; i < 8; ++i)
#pragma unroll
    for (int j = 0; j < 4; ++j) acc[i][j] = 0.f;

  const int bofs = (wn & 1) * 64;

// full tile = 8 quarters (A q0..q3, B q0..q3)
#define STAGE_TILE(DB, T)                                                 \
  STAGE_Q(&As[DB][0][0],    Ag, m0,       T);                             \
  STAGE_Q(&As[DB][0][4096], Ag, m0 + 64,  T);                             \
  STAGE_Q(&As[DB][1][0],    Ag, m0 + 128, T);                             \
  STAGE_Q(&As[DB][1][4096], Ag, m0 + 192, T);                             \
  STAGE_Q(&Bs[DB][0][0],    Bg, n0,       T);                             \
  STAGE_Q(&Bs[DB][0][4096], Bg, n0 + 64,  T);                             \
  STAGE_Q(&Bs[DB][1][0],    Bg, n0 + 128, T);                             \
  STAGE_Q(&Bs[DB][1][4096], Bg, n0 + 192, T)

  // prologue: tile0 -> dbuf0 (oldest 8 loads), tile1 -> dbuf1
  STAGE_TILE(0, 0);
  STAGE_TILE(1, 1);
  VMC8();          // tile0's 8 landed; tile1's 8 in flight
  BAR();

#define PHASES4(DB, TN, PRE)                                              \
  {                                                                       \
    const u16* Apb = &As[DB][wm][0];                                      \
    const u16* Bpb = &Bs[DB][wn >> 1][0];                                 \
    /* ph0: (a0,b0); no stages */                                         \
    RD_A(a0, Apb, 0);                                                     \
    RD_B(b0, Bpb, bofs, 0);                                               \
    BAR();                                                                \
    LGKM0();                                                              \
    MM(a0, b0, 0, 0);                                                     \
    SB0();                                                                \
    BAR();                                                                \
    /* ph1: (a0,b1); stage A q0,q2 of TN (a0 regions, last read ph0) */   \
    RD_B(b1, Bpb, bofs, 1);                                               \
    if (PRE) { STAGE_Q(&As[DB][0][0], Ag, m0,       TN);                  \
               STAGE_Q(&As[DB][1][0], Ag, m0 + 128, TN); }                \
    BAR();                                                                \
    LGKM0();                                                              \
    MM(a0, b1, 0, 1);                                                     \
    SB0();                                                                \
    BAR();                                                                \
    /* ph2: (a1,b1); stage all B quarters of TN (B fully read after ph1) */ \
    RD_A(a1, Apb, 1);                                                     \
    if (PRE) { STAGE_Q(&Bs[DB][0][0],    Bg, n0,       TN);               \
               STAGE_Q(&Bs[DB][0][4096], Bg, n0 + 64,  TN);               \
               STAGE_Q(&Bs[DB][1][0],    Bg, n0 + 128, TN);               \
               STAGE_Q(&Bs[DB][1][4096], Bg, n0 + 192, TN); }             \
    BAR();                                                                \
    LGKM0();                                                              \
    MM(a1, b1, 1, 1);                                                     \
    SB0();                                                                \
    BAR();                                                                \
    /* ph3: (a1,b0) regs only; stage A q1,q3 of TN (a1 regions, read ph2) */ \
    if (PRE) { STAGE_Q(&As[DB][0][4096], Ag, m0 + 64,  TN);               \
               STAGE_Q(&As[DB][1][4096], Ag, m0 + 192, TN); }             \
    BAR();                                                                \
    LGKM0();                                                              \
    MM(a1, b0, 1, 0);                                                     \
    SB0();                                                                \
    if (PRE) { VMC8(); } else { VMC0(); }                                 \
    BAR();                                                                \
  }

  for (int it = 0; it < NT / 2; ++it) {
    const int t0 = 2 * it;
    const bool pre = (t0 + 2 < NT);
    f16x8 a0[4][2], a1[4][2], b0[2][2], b1[2][2];
    PHASES4(0, t0 + 2, pre)   // tile 2i
    PHASES4(1, t0 + 3, pre)   // tile 2i+1
  }
#undef PHASES4
#undef STAGE_TILE
#undef STAGE_Q
#undef BAR
#undef LGKM0
#undef SB0
#undef VMC8
#undef VMC0
#undef RD_A
#undef RD_B
#undef MM

  // ---------------- epilogues (wave tile rows wm*128, cols wn*64) ----------------
  if (EPI == 2) {
    float bv[4];
#pragma unroll
    for (int cf = 0; cf < 4; ++cf) bv[cf] = bias[n0 + wn * 64 + cf * 16 + l15];
    const int region = n0 >> 10;
    const int ncol0 = (n0 & 1023) + wn * 64;
    if (region < 2) {
      u16* dst = region ? D1 : D0;
#pragma unroll
      for (int rf = 0; rf < 8; ++rf) {
        const int m = m0 + wm * 128 + rf * 16 + lhi * 4;
#pragma unroll
        for (int r = 0; r < 4; ++r)
#pragma unroll
          for (int cf = 0; cf < 4; ++cf)
            dst[(size_t)(m + r) * 1024 + ncol0 + cf * 16 + l15] = h1(acc[rf][cf][r] + bv[cf]);
      }
    } else {
#pragma unroll
      for (int rf = 0; rf < 8; ++rf) {
        const int m = m0 + wm * 128 + rf * 16 + lhi * 4;
        const int bb = m >> 12, s = m & 4095;
#pragma unroll
        for (int cf = 0; cf < 4; ++cf) {
          const int dcol = ncol0 + cf * 16 + l15;
          uint2 v;
          v.x = pk2h(acc[rf][cf][0] + bv[cf], acc[rf][cf][1] + bv[cf]);
          v.y = pk2h(acc[rf][cf][2] + bv[cf], acc[rf][cf][3] + bv[cf]);
          *(uint2*)&D2[(size_t)(bb * 1024 + dcol) * 4096 + s] = v;
        }
      }
    }
  } else if (EPI == 0) {
#pragma unroll
    for (int rf = 0; rf < 8; ++rf) {
      const int m = m0 + wm * 128 + rf * 16 + lhi * 4;
#pragma unroll
      for (int r = 0; r < 4; ++r)
#pragma unroll
        for (int cf = 0; cf < 4; ++cf) {
          const int n = n0 + wn * 64 + cf * 16 + l15;
          D0[(size_t)blockIdx.z * strC + (size_t)(m + r) * ldc + n] = h1(acc[rf][cf][r] * 0.03125f);
        }
    }
  } else {
#pragma unroll
    for (int rf = 0; rf < 8; ++rf) {
      const int m = m0 + wm * 128 + rf * 16 + lhi * 4;
#pragma unroll
      for (int r = 0; r < 4; ++r)
#pragma unroll
        for (int cf = 0; cf < 4; ++cf) {
          const int n = n0 + wn * 64 + cf * 16 + l15;
          Df[(size_t)blockIdx.z * strC + (size_t)(m + r) * ldc + n] = acc[rf][cf][r];
        }
    }
  }
}

// ---------------- row softmax, in place, f16. 1 block = 1 row of 4096 ----------------
__global__ __launch_bounds__(256) void softmax_k(u16* __restrict__ S) {
  const int tid = threadIdx.x, lane = tid & 63, wid = tid >> 6;
  u16* rp = S + (size_t)blockIdx.x * 4096;
  __shared__ float redm[4], reds[4];

  uint4 a = *(const uint4*)(rp + tid * 8);
  uint4 b = *(const uint4*)(rp + 2048 + tid * 8);
  float v[16];
  {
    union { uint4 q; u16 s[8]; } ua, ub;
    ua.q = a; ub.q = b;
#pragma unroll
    for (int i = 0; i < 8; ++i) { v[i] = h2f(ua.s[i]); v[8 + i] = h2f(ub.s[i]); }
  }
  float m = v[0];
#pragma unroll
  for (int i = 1; i < 16; ++i) m = fmaxf(m, v[i]);
#pragma unroll
  for (int o = 32; o; o >>= 1) m = fmaxf(m, __shfl_xor(m, o, 64));
  if (lane == 0) redm[wid] = m;
  __syncthreads();
  m = fmaxf(fmaxf(redm[0], redm[1]), fmaxf(redm[2], redm[3]));

  float s = 0.f;
#pragma unroll
  for (int i = 0; i < 16; ++i) { v[i] = EXP2F((v[i] - m) * LOG2E); s += v[i]; }
#pragma unroll
  for (int o = 32; o; o >>= 1) s += __shfl_xor(s, o, 64);
  if (lane == 0) reds[wid] = s;
  __syncthreads();
  const float inv = 1.0f / (reds[0] + reds[1] + reds[2] + reds[3]);

  uint4 oa, ob;
  oa.x = pk2h(v[0] * inv, v[1] * inv);   oa.y = pk2h(v[2] * inv, v[3] * inv);
  oa.z = pk2h(v[4] * inv, v[5] * inv);   oa.w = pk2h(v[6] * inv, v[7] * inv);
  ob.x = pk2h(v[8] * inv, v[9] * inv);   ob.y = pk2h(v[10] * inv, v[11] * inv);
  ob.z = pk2h(v[12] * inv, v[13] * inv); ob.w = pk2h(v[14] * inv, v[15] * inv);
  *(uint4*)(rp + tid * 8) = oa;
  *(uint4*)(rp + 2048 + tid * 8) = ob;
}

// ---------------- host ----------------
extern "C" void kernel_launch(void* const* d_in, const int* in_sizes, int n_in,
                              void* d_out, int out_size, void* d_ws, size_t ws_size,
                              hipStream_t stream) {
  const float* X = (const float*)d_in[0];   // [4,4096,1024]
  const float* W = (const float*)d_in[1];   // [3072,1024]
  const float* b = (const float*)d_in[2];   // [3072]
  float* out = (float*)d_out;               // [4,4096,1024] fp32
  char* ws = (char*)d_ws;

  const size_t SB = (size_t)4096 * 4096 * 2;          // S bytes per batch
  const size_t QB = (size_t)4096 * 1024 * 2;
  const size_t WFB = (size_t)3072 * 1024 * 2;
  int NB = 1;
  if (ws_size >= 4 * SB + WFB + 12 * QB) NB = 4;
  else if (ws_size >= 2 * SB + WFB + 12 * QB) NB = 2;

  u16* S  = (u16*)(ws);
  u16* Xf = (u16*)(ws);                               // overlay; dead after QKV proj
  u16* Wf = (u16*)(ws + (size_t)NB * SB);
  u16* Qf = (u16*)(ws + (size_t)NB * SB + WFB);
  u16* Kf = (u16*)(ws + (size_t)NB * SB + WFB + 4 * QB);
  u16* Vt = (u16*)(ws + (size_t)NB * SB + WFB + 8 * QB);

  cast_f16_k<<<8192, 256, 0, stream>>>(X, Xf, 16777216 / 8);
  cast_f16_k<<<1536, 256, 0, stream>>>(W, Wf, 3145728 / 8);

  // QKV projection: M=16384, N=3072, K=1024
  gemm8p<1024, 2><<<dim3(64, 12, 1), 512, 0, stream>>>(
      Xf, Wf, b, Qf, Kf, Vt, nullptr, 0, 0, 0, 0);

  const size_t strQ = (size_t)4096 * 1024;
  const size_t strS = (size_t)4096 * 4096;
  const size_t strV = (size_t)1024 * 4096;
  for (int g = 0; g < 4; g += NB) {
    const u16* Qg = Qf + (size_t)g * strQ;
    const u16* Kg = Kf + (size_t)g * strQ;
    const u16* Vg = Vt + (size_t)g * strV;
    float* Og = out + (size_t)g * strQ;
    // S = Q K^T / 32  [4096x4096] x NB
    gemm8p<1024, 0><<<dim3(16, 16, NB), 512, 0, stream>>>(
        Qg, Kg, nullptr, S, nullptr, nullptr, nullptr, 4096, strQ, strQ, strS);
    softmax_k<<<4096 * NB, 256, 0, stream>>>(S);
    // O = P Vt^T  [4096x1024] x NB
    gemm8p<4096, 1><<<dim3(16, 4, NB), 512, 0, stream>>>(
        S, Vg, nullptr, nullptr, nullptr, nullptr, Og, 1024, strS, strV, strQ);
  }
}